// Round 3
// baseline (2922.635 us; speedup 1.0000x reference)
//
#include <hip/hip_runtime.h>

#define NB 256      // batch
#define TT 1000     // total timesteps
#define HD 128      // hidden
#define NG 512      // 4*H, PyTorch gate order i,f,g,o
#define SS 8        // K2: timesteps per LDS slab

__device__ __forceinline__ float sigf(float x) {
    return 1.f / (1.f + __expf(-x));            // x->-inf: 1/inf=0 ; x->+inf: 1
}
__device__ __forceinline__ float tanhfast(float x) {
    float e = __expf(-2.f * x);                 // 2*sigmoid(2x)-1, NaN-safe both tails
    return 2.f / (1.f + e) - 1.f;
}

// ---------------- K1: layer-0 recurrence, W_hh_l0 in registers ----------------
// launch_bounds(512,1): grid is 1 block/CU anyway; 2 waves/SIMD -> 256 VGPR budget
// so w[128] stays register-resident (was demoted at (512,2)'s 128-VGPR cap).
__global__ __launch_bounds__(512, 1)
void lstm_layer0(const float* __restrict__ x,
                 const float* __restrict__ Wih, const float* __restrict__ Whh,
                 const float* __restrict__ bih, const float* __restrict__ bhh,
                 float* __restrict__ h1c,
                 float* __restrict__ hstate, float* __restrict__ cstate,
                 int t0, int len)
{
    __shared__ __align__(16) float h_lds[HD];
    __shared__ float gbuf[NG];
    __shared__ float x_lds[3 * TT];   // 12 KB: whole chunk of this batch row's input
    const int j = threadIdx.x;
    const int b = blockIdx.x;

    float4 wv[HD/4];   // W_hh row j, fully in VGPRs (static indices only)
    {
        const float4* wr = (const float4*)(Whh + (size_t)j * HD);
        #pragma unroll
        for (int q = 0; q < HD/4; ++q) wv[q] = wr[q];
    }
    const float wx0 = Wih[j*3+0], wx1 = Wih[j*3+1], wx2 = Wih[j*3+2];
    const float bias = bih[j] + bhh[j];

    for (int idx = j; idx < 3*len; idx += 512)
        x_lds[idx] = x[((size_t)b*TT + t0)*3 + idx];

    float c = 0.f, hcur = 0.f;
    if (j < HD) {
        if (t0 != 0) { hcur = hstate[b*HD+j]; c = cstate[b*HD+j]; }
        h_lds[j] = hcur;
    }
    __syncthreads();

    const int gtype = j >> 7;   // 0:i 1:f 2:g 3:o — wave-uniform (128 per gate)
    for (int tc = 0; tc < len; ++tc) {
        float a0=0.f,a1=0.f,a2=0.f,a3=0.f;
        const float4* h4 = (const float4*)h_lds;   // uniform addr -> LDS broadcast
        #pragma unroll
        for (int q = 0; q < HD/4; ++q) {
            float4 hv = h4[q];
            a0 = fmaf(hv.x, wv[q].x, a0);
            a1 = fmaf(hv.y, wv[q].y, a1);
            a2 = fmaf(hv.z, wv[q].z, a2);
            a3 = fmaf(hv.w, wv[q].w, a3);
        }
        float acc = bias + ((a0+a1)+(a2+a3));
        acc = fmaf(wx0, x_lds[3*tc+0], acc);
        acc = fmaf(wx1, x_lds[3*tc+1], acc);
        acc = fmaf(wx2, x_lds[3*tc+2], acc);
        float act = (gtype == 2) ? tanhfast(acc) : sigf(acc);
        gbuf[j] = act;
        __syncthreads();                 // barrier A: gates visible
        if (j < HD) {
            float ig = gbuf[j], fg = gbuf[HD+j], gg = gbuf[2*HD+j], og = gbuf[3*HD+j];
            c = fmaf(fg, c, ig*gg);
            hcur = og * tanhfast(c);
            h_lds[j] = hcur;
            h1c[((size_t)b*len + tc)*HD + j] = hcur;
        }
        __syncthreads();                 // barrier B: new h visible
    }
    if (j < HD) { hstate[b*HD+j] = hcur; cstate[b*HD+j] = c; }
}

// ---------------- K2: xg1 = h1 @ W_ih_l1^T + biases, W_ih_l1 in registers ----------------
// No recurrence: stage SS rows per LDS slab, 2 barriers per SS steps.
__global__ __launch_bounds__(512, 1)
void xgate_gemm(const float* __restrict__ h1c,
                const float* __restrict__ Wih1,
                const float* __restrict__ bih1, const float* __restrict__ bhh1,
                float* __restrict__ xg1c, int len)
{
    __shared__ __align__(16) float hrows[SS][HD];   // 4 KB
    const int j = threadIdx.x;
    const int b = blockIdx.x;
    float4 wv[HD/4];
    {
        const float4* wr = (const float4*)(Wih1 + (size_t)j * HD);
        #pragma unroll
        for (int q = 0; q < HD/4; ++q) wv[q] = wr[q];
    }
    const float bias = bih1[j] + bhh1[j];

    for (int ts = 0; ts < len; ts += SS) {
        const int ns = (len - ts < SS) ? (len - ts) : SS;
        __syncthreads();   // previous slab's reads complete before overwrite
        for (int idx = j; idx < ns * HD; idx += 512)
            hrows[idx >> 7][idx & 127] = h1c[((size_t)b*len + ts)*HD + idx];
        __syncthreads();   // slab visible
        for (int s = 0; s < ns; ++s) {
            float a0=0.f,a1=0.f,a2=0.f,a3=0.f;
            const float4* h4 = (const float4*)hrows[s];   // uniform addr broadcast
            #pragma unroll
            for (int q = 0; q < HD/4; ++q) {
                float4 hv = h4[q];
                a0=fmaf(hv.x,wv[q].x,a0); a1=fmaf(hv.y,wv[q].y,a1);
                a2=fmaf(hv.z,wv[q].z,a2); a3=fmaf(hv.w,wv[q].w,a3);
            }
            xg1c[((size_t)b*len + ts + s)*NG + j] = bias + ((a0+a1)+(a2+a3));
        }
    }
}

// ---------------- K3: layer-1 recurrence + fused FC head ----------------
__global__ __launch_bounds__(512, 1)
void lstm_layer1(const float* __restrict__ xg1c,
                 const float* __restrict__ Whh1,
                 const float* __restrict__ fcw, const float* __restrict__ fcb,
                 float* __restrict__ y,
                 float* __restrict__ hstate, float* __restrict__ cstate,
                 int t0, int len)
{
    __shared__ __align__(16) float h2_lds[2][HD];
    __shared__ float gbuf[NG];
    const int j = threadIdx.x;
    const int b = blockIdx.x;
    const int lane = j & 63;
    float4 wv[HD/4];   // W_hh_l1 row j
    {
        const float4* wr = (const float4*)(Whh1 + (size_t)j * HD);
        #pragma unroll
        for (int q = 0; q < HD/4; ++q) wv[q] = wr[q];
    }
    // FC-head weights live in wave 2 (threads 128..191 — exactly one wave)
    float f0a=0,f0b=0,f1a=0,f1b=0,f2a=0,f2b=0,fb=0;
    const bool ywave = (j >= 128 && j < 192);
    if (ywave) {
        f0a = fcw[0*HD+lane]; f0b = fcw[0*HD+64+lane];
        f1a = fcw[1*HD+lane]; f1b = fcw[1*HD+64+lane];
        f2a = fcw[2*HD+lane]; f2b = fcw[2*HD+64+lane];
        if (lane < 3) fb = fcb[lane];
    }
    float c = 0.f, hcur = 0.f;
    if (j < HD) {
        if (t0 != 0) { hcur = hstate[b*HD+j]; c = cstate[b*HD+j]; }
        h2_lds[1][j] = hcur;   // read-buffer for tc=0 is index 1
        h2_lds[0][j] = 0.f;
    }
    __syncthreads();
    const int gtype = j >> 7;
    float xg_cur = xg1c[((size_t)b*len + 0)*NG + j];
    for (int tc = 0; tc < len; ++tc) {
        float xg_nxt = 0.f;
        if (tc+1 < len) xg_nxt = xg1c[((size_t)b*len + tc+1)*NG + j]; // prefetch
        float a0=0.f,a1=0.f,a2=0.f,a3=0.f;
        const float4* h4 = (const float4*)h2_lds[(tc+1)&1];
        #pragma unroll
        for (int q = 0; q < HD/4; ++q) {
            float4 hv = h4[q];
            a0=fmaf(hv.x,wv[q].x,a0); a1=fmaf(hv.y,wv[q].y,a1);
            a2=fmaf(hv.z,wv[q].z,a2); a3=fmaf(hv.w,wv[q].w,a3);
        }
        float acc = xg_cur + ((a0+a1)+(a2+a3));
        float act = (gtype == 2) ? tanhfast(acc) : sigf(acc);
        gbuf[j] = act;
        __syncthreads();                                // barrier A
        if (j < HD) {                                   // update wave-pair
            float ig = gbuf[j], fg = gbuf[HD+j], gg = gbuf[2*HD+j], og = gbuf[3*HD+j];
            c = fmaf(fg, c, ig*gg);
            hcur = og * tanhfast(c);
            h2_lds[tc&1][j] = hcur;
        } else if (ywave && tc > 0) {                   // FC head for step tc-1 (parallel w/ update)
            const float* hp = h2_lds[(tc+1)&1];         // == (tc-1)&1: h2[tc-1]
            float ha = hp[lane], hb = hp[64+lane];
            float y0 = ha*f0a + hb*f0b;
            float y1 = ha*f1a + hb*f1b;
            float y2 = ha*f2a + hb*f2b;
            #pragma unroll
            for (int m = 1; m < 64; m <<= 1) {
                y0 += __shfl_xor(y0, m);
                y1 += __shfl_xor(y1, m);
                y2 += __shfl_xor(y2, m);
            }
            if (lane < 3) {
                float yv = (lane==0) ? y0 : (lane==1) ? y1 : y2;
                y[((size_t)b*TT + (t0+tc-1))*3 + lane] = yv + fb;
            }
        }
        __syncthreads();                                // barrier B
        xg_cur = xg_nxt;
    }
    // tail: head for the chunk's last step
    if (ywave) {
        const float* hp = h2_lds[(len+1)&1];   // == (len-1)&1
        float ha = hp[lane], hb = hp[64+lane];
        float y0 = ha*f0a + hb*f0b;
        float y1 = ha*f1a + hb*f1b;
        float y2 = ha*f2a + hb*f2b;
        #pragma unroll
        for (int m = 1; m < 64; m <<= 1) {
            y0 += __shfl_xor(y0, m); y1 += __shfl_xor(y1, m); y2 += __shfl_xor(y2, m);
        }
        if (lane < 3) {
            float yv = (lane==0) ? y0 : (lane==1) ? y1 : y2;
            y[((size_t)b*TT + (t0+len-1))*3 + lane] = yv + fb;
        }
    }
    if (j < HD) { hstate[b*HD+j] = hcur; cstate[b*HD+j] = c; }
}

extern "C" void kernel_launch(void* const* d_in, const int* in_sizes, int n_in,
                              void* d_out, int out_size, void* d_ws, size_t ws_size,
                              hipStream_t stream)
{
    const float* x    = (const float*)d_in[0];
    const float* Wih0 = (const float*)d_in[1];
    const float* Whh0 = (const float*)d_in[2];
    const float* bih0 = (const float*)d_in[3];
    const float* bhh0 = (const float*)d_in[4];
    const float* Wih1 = (const float*)d_in[5];
    const float* Whh1 = (const float*)d_in[6];
    const float* bih1 = (const float*)d_in[7];
    const float* bhh1 = (const float*)d_in[8];
    const float* fcw  = (const float*)d_in[9];
    const float* fcb  = (const float*)d_in[10];
    float* y = (float*)d_out;

    // ws layout: h1 chunk (B*Tc*128 f32) + xg1 chunk (B*Tc*512 f32) + 4 state bufs
    const size_t stateBytes = 4ull * NB * HD * sizeof(float);         // 512 KB
    const size_t perT = (size_t)NB*HD*sizeof(float) + (size_t)NB*NG*sizeof(float); // 655360 B
    long tcl = (ws_size > stateBytes) ? (long)((ws_size - stateBytes) / perT) : 1;
    if (tcl > TT) tcl = TT;
    if (tcl < 1)  tcl = 1;
    const int Tc = (int)tcl;   // derived from ws_size only -> deterministic

    float* h1c  = (float*)d_ws;
    float* xg1c = h1c  + (size_t)NB * Tc * HD;
    float* hs1  = xg1c + (size_t)NB * Tc * NG;
    float* cs1  = hs1 + NB*HD;
    float* hs2  = cs1 + NB*HD;
    float* cs2  = hs2 + NB*HD;

    for (int t0 = 0; t0 < TT; t0 += Tc) {
        const int len = (TT - t0 < Tc) ? (TT - t0) : Tc;
        lstm_layer0<<<dim3(NB), dim3(512), 0, stream>>>(
            x, Wih0, Whh0, bih0, bhh0, h1c, hs1, cs1, t0, len);
        xgate_gemm<<<dim3(NB), dim3(512), 0, stream>>>(
            h1c, Wih1, bih1, bhh1, xg1c, len);
        lstm_layer1<<<dim3(NB), dim3(512), 0, stream>>>(
            xg1c, Whh1, fcw, fcb, y, hs2, cs2, t0, len);
    }
}

// Round 4
// 2695.119 us; speedup vs baseline: 1.0844x; 1.0844x over previous
//
#include <hip/hip_runtime.h>

#define NB 256      // batch
#define TT 1000     // total timesteps
#define HD 128      // hidden
#define NG 512      // 4*H, PyTorch gate order i,f,g,o
#define SS 8        // K2: timesteps per LDS slab

__device__ __forceinline__ float sigf(float x) {
    return 1.f / (1.f + __expf(-x));            // x->-inf: 1/inf=0 ; x->+inf: 1
}
__device__ __forceinline__ float tanhfast(float x) {
    float e = __expf(-2.f * x);                 // 2*sigmoid(2x)-1, NaN-safe both tails
    return 2.f / (1.f + e) - 1.f;
}

// ---------------- K1: layer-0 recurrence, W_hh_l0 in registers ----------------
// Runs at ~225 ns/step (VALU floor) — this structure is the proven-good template.
__global__ __launch_bounds__(512, 1)
void lstm_layer0(const float* __restrict__ x,
                 const float* __restrict__ Wih, const float* __restrict__ Whh,
                 const float* __restrict__ bih, const float* __restrict__ bhh,
                 float* __restrict__ h1c,
                 float* __restrict__ hstate, float* __restrict__ cstate,
                 int t0, int len)
{
    __shared__ __align__(16) float h_lds[HD];
    __shared__ float gbuf[NG];
    __shared__ float x_lds[3 * TT];   // 12 KB: whole chunk of this batch row's input
    const int j = threadIdx.x;
    const int b = blockIdx.x;

    float4 wv[HD/4];   // W_hh row j (static indices only)
    {
        const float4* wr = (const float4*)(Whh + (size_t)j * HD);
        #pragma unroll
        for (int q = 0; q < HD/4; ++q) wv[q] = wr[q];
    }
    const float wx0 = Wih[j*3+0], wx1 = Wih[j*3+1], wx2 = Wih[j*3+2];
    const float bias = bih[j] + bhh[j];

    for (int idx = j; idx < 3*len; idx += 512)
        x_lds[idx] = x[((size_t)b*TT + t0)*3 + idx];

    float c = 0.f, hcur = 0.f;
    if (j < HD) {
        if (t0 != 0) { hcur = hstate[b*HD+j]; c = cstate[b*HD+j]; }
        h_lds[j] = hcur;
    }
    __syncthreads();

    const int gtype = j >> 7;   // 0:i 1:f 2:g 3:o — wave-uniform (128 per gate)
    for (int tc = 0; tc < len; ++tc) {
        float a0=0.f,a1=0.f,a2=0.f,a3=0.f;
        const float4* h4 = (const float4*)h_lds;   // uniform addr -> LDS broadcast
        #pragma unroll
        for (int q = 0; q < HD/4; ++q) {
            float4 hv = h4[q];
            a0 = fmaf(hv.x, wv[q].x, a0);
            a1 = fmaf(hv.y, wv[q].y, a1);
            a2 = fmaf(hv.z, wv[q].z, a2);
            a3 = fmaf(hv.w, wv[q].w, a3);
        }
        float acc = bias + ((a0+a1)+(a2+a3));
        acc = fmaf(wx0, x_lds[3*tc+0], acc);
        acc = fmaf(wx1, x_lds[3*tc+1], acc);
        acc = fmaf(wx2, x_lds[3*tc+2], acc);
        float act = (gtype == 2) ? tanhfast(acc) : sigf(acc);
        gbuf[j] = act;
        __syncthreads();                 // barrier A: gates visible
        if (j < HD) {
            float ig = gbuf[j], fg = gbuf[HD+j], gg = gbuf[2*HD+j], og = gbuf[3*HD+j];
            c = fmaf(fg, c, ig*gg);
            hcur = og * tanhfast(c);
            h_lds[j] = hcur;
            h1c[((size_t)b*len + tc)*HD + j] = hcur;
        }
        __syncthreads();                 // barrier B: new h visible
    }
    if (j < HD) { hstate[b*HD+j] = hcur; cstate[b*HD+j] = c; }
}

// ---------------- K2: xg1 = h1 @ W_ih_l1^T + biases, W_ih_l1 in registers ----------------
__global__ __launch_bounds__(512, 1)
void xgate_gemm(const float* __restrict__ h1c,
                const float* __restrict__ Wih1,
                const float* __restrict__ bih1, const float* __restrict__ bhh1,
                float* __restrict__ xg1c, int len)
{
    __shared__ __align__(16) float hrows[SS][HD];   // 4 KB
    const int j = threadIdx.x;
    const int b = blockIdx.x;
    float4 wv[HD/4];
    {
        const float4* wr = (const float4*)(Wih1 + (size_t)j * HD);
        #pragma unroll
        for (int q = 0; q < HD/4; ++q) wv[q] = wr[q];
    }
    const float bias = bih1[j] + bhh1[j];

    for (int ts = 0; ts < len; ts += SS) {
        const int ns = (len - ts < SS) ? (len - ts) : SS;
        __syncthreads();   // previous slab's reads complete before overwrite
        for (int idx = j; idx < ns * HD; idx += 512)
            hrows[idx >> 7][idx & 127] = h1c[((size_t)b*len + ts)*HD + idx];
        __syncthreads();   // slab visible
        for (int s = 0; s < ns; ++s) {
            float a0=0.f,a1=0.f,a2=0.f,a3=0.f;
            const float4* h4 = (const float4*)hrows[s];   // uniform addr broadcast
            #pragma unroll
            for (int q = 0; q < HD/4; ++q) {
                float4 hv = h4[q];
                a0=fmaf(hv.x,wv[q].x,a0); a1=fmaf(hv.y,wv[q].y,a1);
                a2=fmaf(hv.z,wv[q].z,a2); a3=fmaf(hv.w,wv[q].w,a3);
            }
            xg1c[((size_t)b*len + ts + s)*NG + j] = bias + ((a0+a1)+(a2+a3));
        }
    }
}

// ---------------- K3: layer-1 recurrence (no FC head) — mirrors K1 exactly ----------------
// Writes h2 rows to h2c (aliases h1c: dead after K2). FC head moved to fc_head.
__global__ __launch_bounds__(512, 1)
void lstm_layer1(const float* __restrict__ xg1c,
                 const float* __restrict__ Whh1,
                 float* __restrict__ h2c,
                 float* __restrict__ hstate, float* __restrict__ cstate,
                 int t0, int len)
{
    __shared__ __align__(16) float h_lds[HD];
    __shared__ float gbuf[NG];
    const int j = threadIdx.x;
    const int b = blockIdx.x;
    float4 wv[HD/4];   // W_hh_l1 row j
    {
        const float4* wr = (const float4*)(Whh1 + (size_t)j * HD);
        #pragma unroll
        for (int q = 0; q < HD/4; ++q) wv[q] = wr[q];
    }
    float c = 0.f, hcur = 0.f;
    if (j < HD) {
        if (t0 != 0) { hcur = hstate[b*HD+j]; c = cstate[b*HD+j]; }
        h_lds[j] = hcur;
    }
    __syncthreads();
    const int gtype = j >> 7;
    float xg_cur = xg1c[((size_t)b*len + 0)*NG + j];
    for (int tc = 0; tc < len; ++tc) {
        float xg_nxt = 0.f;
        if (tc+1 < len) xg_nxt = xg1c[((size_t)b*len + tc+1)*NG + j]; // prefetch
        float a0=0.f,a1=0.f,a2=0.f,a3=0.f;
        const float4* h4 = (const float4*)h_lds;
        #pragma unroll
        for (int q = 0; q < HD/4; ++q) {
            float4 hv = h4[q];
            a0=fmaf(hv.x,wv[q].x,a0); a1=fmaf(hv.y,wv[q].y,a1);
            a2=fmaf(hv.z,wv[q].z,a2); a3=fmaf(hv.w,wv[q].w,a3);
        }
        float acc = xg_cur + ((a0+a1)+(a2+a3));
        float act = (gtype == 2) ? tanhfast(acc) : sigf(acc);
        gbuf[j] = act;
        __syncthreads();                 // barrier A
        if (j < HD) {
            float ig = gbuf[j], fg = gbuf[HD+j], gg = gbuf[2*HD+j], og = gbuf[3*HD+j];
            c = fmaf(fg, c, ig*gg);
            hcur = og * tanhfast(c);
            h_lds[j] = hcur;
            h2c[((size_t)b*len + tc)*HD + j] = hcur;
        }
        __syncthreads();                 // barrier B
        xg_cur = xg_nxt;
    }
    if (j < HD) { hstate[b*HD+j] = hcur; cstate[b*HD+j] = c; }
}

// ---------------- K4: y = h2 @ fcw^T + fcb — wave-per-row, deterministic ----------------
__global__ __launch_bounds__(512, 1)
void fc_head(const float* __restrict__ h2c,
             const float* __restrict__ fcw, const float* __restrict__ fcb,
             float* __restrict__ y, int t0, int len)
{
    const int b = blockIdx.x;
    const int wid = threadIdx.x >> 6;   // 0..7
    const int lane = threadIdx.x & 63;
    const float f0a = fcw[0*HD+lane], f0b = fcw[0*HD+64+lane];
    const float f1a = fcw[1*HD+lane], f1b = fcw[1*HD+64+lane];
    const float f2a = fcw[2*HD+lane], f2b = fcw[2*HD+64+lane];
    const float fb = (lane < 3) ? fcb[lane] : 0.f;
    for (int tc = wid; tc < len; tc += 8) {
        const float* hp = h2c + ((size_t)b*len + tc)*HD;
        float ha = hp[lane], hb = hp[64+lane];
        float y0 = ha*f0a + hb*f0b;
        float y1 = ha*f1a + hb*f1b;
        float y2 = ha*f2a + hb*f2b;
        #pragma unroll
        for (int m = 1; m < 64; m <<= 1) {
            y0 += __shfl_xor(y0, m);
            y1 += __shfl_xor(y1, m);
            y2 += __shfl_xor(y2, m);
        }
        if (lane < 3) {
            float yv = (lane==0) ? y0 : (lane==1) ? y1 : y2;
            y[((size_t)b*TT + (t0+tc))*3 + lane] = yv + fb;
        }
    }
}

extern "C" void kernel_launch(void* const* d_in, const int* in_sizes, int n_in,
                              void* d_out, int out_size, void* d_ws, size_t ws_size,
                              hipStream_t stream)
{
    const float* x    = (const float*)d_in[0];
    const float* Wih0 = (const float*)d_in[1];
    const float* Whh0 = (const float*)d_in[2];
    const float* bih0 = (const float*)d_in[3];
    const float* bhh0 = (const float*)d_in[4];
    const float* Wih1 = (const float*)d_in[5];
    const float* Whh1 = (const float*)d_in[6];
    const float* bih1 = (const float*)d_in[7];
    const float* bhh1 = (const float*)d_in[8];
    const float* fcw  = (const float*)d_in[9];
    const float* fcb  = (const float*)d_in[10];
    float* y = (float*)d_out;

    // ws layout: h1 chunk (B*Tc*128 f32) + xg1 chunk (B*Tc*512 f32) + 4 state bufs
    const size_t stateBytes = 4ull * NB * HD * sizeof(float);         // 512 KB
    const size_t perT = (size_t)NB*HD*sizeof(float) + (size_t)NB*NG*sizeof(float); // 655360 B
    long tcl = (ws_size > stateBytes) ? (long)((ws_size - stateBytes) / perT) : 1;
    if (tcl > TT) tcl = TT;
    if (tcl < 1)  tcl = 1;
    const int Tc = (int)tcl;   // derived from ws_size only -> deterministic

    float* h1c  = (float*)d_ws;
    float* xg1c = h1c  + (size_t)NB * Tc * HD;
    float* hs1  = xg1c + (size_t)NB * Tc * NG;
    float* cs1  = hs1 + NB*HD;
    float* hs2  = cs1 + NB*HD;
    float* cs2  = hs2 + NB*HD;
    float* h2c  = h1c;   // h1c is dead after K2 of the same chunk — reuse for h2

    for (int t0 = 0; t0 < TT; t0 += Tc) {
        const int len = (TT - t0 < Tc) ? (TT - t0) : Tc;
        lstm_layer0<<<dim3(NB), dim3(512), 0, stream>>>(
            x, Wih0, Whh0, bih0, bhh0, h1c, hs1, cs1, t0, len);
        xgate_gemm<<<dim3(NB), dim3(512), 0, stream>>>(
            h1c, Wih1, bih1, bhh1, xg1c, len);
        lstm_layer1<<<dim3(NB), dim3(512), 0, stream>>>(
            xg1c, Whh1, h2c, hs2, cs2, t0, len);
        fc_head<<<dim3(NB), dim3(512), 0, stream>>>(
            h2c, fcw, fcb, y, t0, len);
    }
}